// Round 7
// baseline (2073.690 us; speedup 1.0000x reference)
//
#include <hip/hip_runtime.h>
#include <hip/hip_bf16.h>
#include <stdint.h>

// Problem constants
#define TT 256
#define BB 64
#define AA 512
#define II 1024
#define HH 1024
#define LL 2
// derived
#define BH 65536        // B*H
#define B4H 262144      // B*4H
#define OUT_HL 16777216
#define OUT_CL (16777216 + 131072)
#define NBLK 256

typedef __attribute__((ext_vector_type(8))) short bf16x8;
typedef __attribute__((ext_vector_type(4))) float f32x4;
typedef __attribute__((ext_vector_type(4))) unsigned int u32x4;
typedef __attribute__((ext_vector_type(2))) unsigned int u32x2;

__device__ __forceinline__ ushort f2bf(float v) {
    union { float f; uint32_t u; } x; x.f = v;
    uint32_t r = x.u + 0x7fff + ((x.u >> 16) & 1);
    return (ushort)(r >> 16);
}

__device__ __forceinline__ float sigf(float x) {   // 1/(1+e^-x), saturation-safe
    return 1.f / (1.f + __expf(-x));
}

// Fragment-major layout for [64][1024] bf16 activation slabs:
//   off(b,k) = (b>>4)*16384 + (k>>5)*512 + ((k>>3)&3)*128 + (b&15)*8 + (k&7)
// A wave loading m-tile m, k-tile kt reads 64 lanes x 16B CONTIGUOUS 1KB at
//   slab + m*16384 + kt*512 + lane*8.

// Build Wt[l][col'][k] bf16, col' = u*4+g for source column col=g*1024+u.
// sc stores: region is later reused as the layer-1 h ring (plain cached reads).
__global__ __launch_bounds__(256) void k_prep_wt(const float* __restrict__ wih,
                                                 const float* __restrict__ whh,
                                                 ushort* __restrict__ Wt) {
    __shared__ ushort tile[64][65];
    const int l = blockIdx.z;
    const int k0 = blockIdx.x * 64;    // 0..2047
    const int col0 = blockIdx.y * 64;  // 0..4095
    const int tid = threadIdx.x;
    const int cl = tid & 63, ks = tid >> 6;
    const float* src;
    int krow0;
    if (k0 < 1024) { src = wih + (size_t)l * 1024 * 4096; krow0 = k0; }
    else           { src = whh + (size_t)l * 1024 * 4096; krow0 = k0 - 1024; }
#pragma unroll
    for (int i = 0; i < 16; ++i) {
        int kl = ks + i * 4;
        tile[kl][cl] = f2bf(src[(size_t)(krow0 + kl) * 4096 + col0 + cl]);
    }
    __syncthreads();
    const int g0 = col0 >> 10, ub = col0 & 1023;
    ushort* dst = Wt + (size_t)l * 4096 * 2048;
    const int klane = tid & 63;
#pragma unroll
    for (int i = 0; i < 16; ++i) {
        int cl2 = (tid >> 6) + i * 4;
        int row = (ub + cl2) * 4 + g0;
        ushort* p = dst + (size_t)row * 2048 + k0 + klane;
        uint v = (uint)tile[klane][cl2];
        asm volatile("global_store_short %0, %1, off sc0 sc1"
                     :: "v"(p), "v"(v) : "memory");
    }
}

// x -> bf16 fragment-major xbfF[t][...]
__global__ __launch_bounds__(256) void k_cast_x(const float* __restrict__ x,
                                                ushort* __restrict__ xbfF) {
    int i = blockIdx.x * 256 + threadIdx.x;   // [256 t][64 b][128 k8]
    int k8 = i & 127, b = (i >> 7) & 63, t = i >> 13;
    const float4* xs = (const float4*)(x + (((size_t)t * 64 + b) * 1024 + k8 * 8));
    float4 a = xs[0], c = xs[1];
    uint4 pk;
    pk.x = (uint)f2bf(a.x) | ((uint)f2bf(a.y) << 16);
    pk.y = (uint)f2bf(a.z) | ((uint)f2bf(a.w) << 16);
    pk.z = (uint)f2bf(c.x) | ((uint)f2bf(c.y) << 16);
    pk.w = (uint)f2bf(c.z) | ((uint)f2bf(c.w) << 16);
    size_t off = (size_t)t * 65536 + (size_t)(b >> 4) * 16384 +
                 (size_t)(k8 >> 2) * 512 + (size_t)(k8 & 3) * 128 + (size_t)(b & 15) * 8;
    *(uint4*)(xbfF + off) = pk;
}

// const[l][b][col] = a0[b,:] @ W_ah[l][:,col] + bias_ah + bias_ih + bias_hh
__global__ __launch_bounds__(256) void k_const(const float* __restrict__ attn,
                                               const float* __restrict__ wah,
                                               const float* __restrict__ bah,
                                               const float* __restrict__ bih,
                                               const float* __restrict__ bhh,
                                               float* __restrict__ constg) {
    const int tid = threadIdx.x;
    const int col = blockIdx.x * 256 + tid;
    const int b0 = blockIdx.y * 8;
    const int l = blockIdx.z;
    const float* W = wah + (size_t)l * 512 * 4096;
    float acc[8] = {0.f, 0.f, 0.f, 0.f, 0.f, 0.f, 0.f, 0.f};
    for (int k = 0; k < 512; ++k) {
        float wv = W[(size_t)k * 4096 + col];
#pragma unroll
        for (int j = 0; j < 8; ++j) acc[j] += attn[(b0 + j) * 512 + k] * wv;
    }
    float bias = bah[l * 4096 + col] + bih[l * 4096 + col] + bhh[l * 4096 + col];
    float* cg = constg + (size_t)l * B4H;
#pragma unroll
    for (int j = 0; j < 8; ++j) cg[(size_t)(b0 + j) * 4096 + col] = acc[j] + bias;
}

// h0 -> fragment-major initial slots
__global__ __launch_bounds__(256) void k_init(const float* __restrict__ h0,
                                              ushort* __restrict__ hs0F,
                                              ushort* __restrict__ h1s0,
                                              unsigned* __restrict__ flags) {
    int i = blockIdx.x * 256 + threadIdx.x;   // [2 l][64 b][128 k8] = 16384
    if (i < 16384) {
        int k8 = i & 127, b = (i >> 7) & 63, l = i >> 13;
        const float* src = h0 + ((size_t)(l * 64 + b) * 1024 + k8 * 8);
        uint4 pk;
        pk.x = (uint)f2bf(src[0]) | ((uint)f2bf(src[1]) << 16);
        pk.y = (uint)f2bf(src[2]) | ((uint)f2bf(src[3]) << 16);
        pk.z = (uint)f2bf(src[4]) | ((uint)f2bf(src[5]) << 16);
        pk.w = (uint)f2bf(src[6]) | ((uint)f2bf(src[7]) << 16);
        size_t off = (size_t)(b >> 4) * 16384 + (size_t)(k8 >> 2) * 512 +
                     (size_t)(k8 & 3) * 128 + (size_t)(b & 15) * 8;
        *(uint4*)((l == 0 ? hs0F : h1s0) + off) = pk;
    }
    if (i < NBLK) flags[i] = 0u;
}

// ---- inline-asm helpers ----
#define ISSUE(BUF, BASE)                                                       \
    do {                                                                       \
        _Pragma("unroll")                                                      \
        for (int _i = 0; _i < 8; ++_i)                                         \
            asm volatile("global_load_dwordx4 %0, %1, off"                     \
                         : "=v"(BUF[_i]) : "v"((BASE) + _i * 512));            \
    } while (0)

// Wait (N outstanding allowed), then 8 A-frags x 2 n-tiles = 16 MFMAs.
#define CONSUME2(BUF, c, N)                                                    \
    do {                                                                       \
        asm volatile("s_waitcnt vmcnt(" #N ")" ::: "memory");                  \
        __builtin_amdgcn_sched_barrier(0x100);                                 \
        _Pragma("unroll")                                                      \
        for (int _i = 0; _i < 8; ++_i) {                                       \
            int _ktg = kh * 32 + (c) * 8 + _i;                                 \
            bf16x8 _b0 = *(const bf16x8*)(wlds + (size_t)_ktg * 1024 + lane * 8);       \
            bf16x8 _b1 = *(const bf16x8*)(wlds + (size_t)_ktg * 1024 + 512 + lane * 8); \
            acc0 = __builtin_amdgcn_mfma_f32_16x16x32_bf16(BUF[_i], _b0, acc0, 0, 0, 0);\
            acc1 = __builtin_amdgcn_mfma_f32_16x16x32_bf16(BUF[_i], _b1, acc1, 0, 0, 0);\
        }                                                                      \
    } while (0)

// Each polling wave reads all 128 flags of one layer (2 per lane).
#define POLL(FB, TGT)                                                          \
    do {                                                                       \
        const unsigned* _fp = (FB) + lane * 2;                                 \
        while (true) {                                                         \
            u32x2 _f;                                                          \
            asm volatile("global_load_dwordx2 %0, %1, off sc0 sc1\n\t"         \
                         "s_waitcnt vmcnt(0)"                                  \
                         : "=v"(_f) : "v"(_fp) : "memory");                    \
            if (__all(_f.x >= (TGT) && _f.y >= (TGT))) break;                  \
            __builtin_amdgcn_s_sleep(2);                                       \
        }                                                                      \
    } while (0)

// Persistent 2-layer LSTM, layer-split: blocks 0-127 = layer0 (8 units each),
// blocks 128-255 = layer1. 512 threads: waves 0-3 k-half 0 (input slab),
// waves 4-7 k-half 1 (h slab); partial sums meet in gt, summed by waves 0-3.
// Layer0 iter s computes t=s; layer1 iter s computes t=s-1.
// Flags: f0[128] layer0 progress, f1[128] layer1. Layer0 waits only f0.
// Wt doubles as the layer-1 h ring after staging (first ring write is gated
// by POLL(f0>=1) which proves all layer-0 staging finished).
__global__ __launch_bounds__(512, 2) void k_persist(
        const ushort* __restrict__ xbfF,
        ushort* __restrict__ hs0F,
        const ushort* __restrict__ h1s0,
        ushort* Wt,                       // staging source + h1 ring (aliased)
        const float* __restrict__ constg,
        const float* __restrict__ c0,
        float* __restrict__ out,
        unsigned* __restrict__ flags) {
    __shared__ ushort wlds[65536];          // [64 ktg][2 nt][64 lane][8] = 128 KiB
    __shared__ float gt[2][4][2][16][17];   // [kh][m][nt][row=b][col] 17 KiB

    const int tid = threadIdx.x;
    const int w = tid >> 6, lane = tid & 63;
    const int kh = w >> 2, m = w & 3;
    const int bid = blockIdx.x;
    const int layer = bid >> 7, ub = bid & 127;
    const int u0g = ub * 8;

    // ---- stage this layer's 32 gate-cols x 2048 k into LDS, lane-order ----
    {
        bf16x8 vst[16];
#pragma unroll
        for (int i = 0; i < 16; ++i) {
            int c = i * 512 + tid;          // 0..8191 chunks of 16B
            int lp = c & 63, nt = (c >> 6) & 1, ktg = c >> 7;
            int colp = u0g * 4 + nt * 16 + (lp & 15);
            int kk = ktg * 32 + (lp >> 4) * 8;
            const ushort* src = Wt + ((size_t)(layer * 4096 + colp)) * 2048 + kk;
            asm volatile("global_load_dwordx4 %0, %1, off sc0 sc1"
                         : "=v"(vst[i]) : "v"(src));
        }
        asm volatile("s_waitcnt vmcnt(0)" ::: "memory");
        __builtin_amdgcn_sched_barrier(0);
#pragma unroll
        for (int i = 0; i < 16; ++i) {
            int c = i * 512 + tid;
            *(bf16x8*)(wlds + (size_t)c * 8) = vst[i];
        }
    }

    const int bl = lane & 15, ud = lane >> 4;

    // epilogue-thread state (waves 0-3): gate consts + c-state for 2 units
    float cgA[4], cgB[4], cA = 0.f, cB = 0.f;
    if (kh == 0) {
        const float* cgp = constg + (size_t)layer * B4H +
                           (size_t)(m * 16 + bl) * 4096 + u0g + ud;
#pragma unroll
        for (int g = 0; g < 4; ++g) { cgA[g] = cgp[g * 1024]; cgB[g] = cgp[g * 1024 + 4]; }
        cA = c0[layer * BH + (m * 16 + bl) * 1024 + u0g + ud];
        cB = c0[layer * BH + (m * 16 + bl) * 1024 + u0g + ud + 4];
    }

    const size_t fro = (size_t)m * 16384 + (size_t)lane * 8;
    const int hoff = m * 16384 + (ub >> 2) * 512 + (ub & 3) * 128 + bl * 8;
    const unsigned* f0 = flags;
    const unsigned* f1 = flags + 128;

    __syncthreads();

    const int sBeg = layer ? 1 : 0;
    const int sEnd = layer ? TT : (TT - 1);
    for (int s = sBeg; s <= sEnd; ++s) {
        const int t1 = s - 1;
        bf16x8 bufA[8], bufB[8], bufC[8], bufD[8];
        f32x4 acc0 = {0.f, 0.f, 0.f, 0.f}, acc1 = {0.f, 0.f, 0.f, 0.f};

        if (kh == 0) {
            const ushort* Al;
            if (layer == 0) {
                Al = xbfF + (size_t)s * 65536 + fro;      // static: no wait
            } else {
                POLL(f0, (unsigned)s);                    // h0 output of t=s-1
                Al = hs0F + (size_t)s * 65536 + fro;
            }
            ISSUE(bufA, Al + 0 * 4096);
            ISSUE(bufB, Al + 1 * 4096);
            ISSUE(bufC, Al + 2 * 4096);
            ISSUE(bufD, Al + 3 * 4096);
        } else {
            const ushort* Al;
            if (layer == 0) {
                if (s >= 1) POLL(f0, (unsigned)s);        // own-layer h state
                Al = hs0F + (size_t)s * 65536 + fro;
            } else {
                if (t1 >= 1) POLL(f1, (unsigned)s);       // own-layer h state
                Al = (t1 == 0 ? h1s0
                              : (const ushort*)Wt + (size_t)(t1 - 1) * 65536) + fro;
            }
            ISSUE(bufA, Al + 0 * 4096);
            ISSUE(bufB, Al + 1 * 4096);
            ISSUE(bufC, Al + 2 * 4096);
            ISSUE(bufD, Al + 3 * 4096);
        }
        CONSUME2(bufA, 0, 24);
        CONSUME2(bufB, 1, 16);
        CONSUME2(bufC, 2, 8);
        CONSUME2(bufD, 3, 0);

        // partial gates -> gt  (C/D map: col = lane&15, row = (lane>>4)*4 + r)
        {
            const int r0 = ud * 4;
#pragma unroll
            for (int r = 0; r < 4; ++r) {
                gt[kh][m][0][r0 + r][bl] = acc0[r];
                gt[kh][m][1][r0 + r][bl] = acc1[r];
            }
        }
        __syncthreads();   // sync1: all partials visible

        float hvA = 0.f, hvB = 0.f, cnA = 0.f, cnB = 0.f;
        if (kh == 0) {
            // thread owns (b = m*16+bl, units u0g+ud and u0g+ud+4)
            float gA[4], gB[4];
#pragma unroll
            for (int g = 0; g < 4; ++g) {
                gA[g] = gt[0][m][0][bl][ud * 4 + g] + gt[1][m][0][bl][ud * 4 + g] + cgA[g];
                gB[g] = gt[0][m][1][bl][ud * 4 + g] + gt[1][m][1][bl][ud * 4 + g] + cgB[g];
            }
            float siA = sigf(gA[0]), sfA = sigf(gA[1]), soA = sigf(gA[3]);
            cnA = sfA * cA + siA * (2.f * sigf(2.f * gA[2]) - 1.f);
            hvA = soA * (2.f * sigf(2.f * cnA) - 1.f);
            cA = cnA;
            float siB = sigf(gB[0]), sfB = sigf(gB[1]), soB = sigf(gB[3]);
            cnB = sfB * cB + siB * (2.f * sigf(2.f * gB[2]) - 1.f);
            hvB = soB * (2.f * sigf(2.f * cnB) - 1.f);
            cB = cnB;
            // pack 8 units per batch row into 16B via shuffles; lanes 0-15 store
            uint hbA = (uint)f2bf(hvA), hbB = (uint)f2bf(hvB);
            uint q0 = __shfl(hbA, bl),      q1 = __shfl(hbA, bl + 16);
            uint q2 = __shfl(hbA, bl + 32), q3 = __shfl(hbA, bl + 48);
            uint q4 = __shfl(hbB, bl),      q5 = __shfl(hbB, bl + 16);
            uint q6 = __shfl(hbB, bl + 32), q7 = __shfl(hbB, bl + 48);
            u32x4 hp;
            hp.x = (q0 & 0xffffu) | (q1 << 16);
            hp.y = (q2 & 0xffffu) | (q3 << 16);
            hp.z = (q4 & 0xffffu) | (q5 << 16);
            hp.w = (q6 & 0xffffu) | (q7 << 16);
            ushort* hdst = (layer == 0 ? hs0F + (size_t)(s + 1) * 65536
                                       : Wt + (size_t)t1 * 65536) + hoff;
            if (lane < 16)
                asm volatile("global_store_dwordx4 %0, %1, off sc0 sc1"
                             :: "v"(hdst), "v"(hp) : "memory");
        }

        // drain h-stores, block barrier, signal own flag
        asm volatile("s_waitcnt vmcnt(0)" ::: "memory");
        __syncthreads();   // sync2
        if (tid == 0) {
            unsigned tgt = (unsigned)(s + 1);
            unsigned* fp = flags + layer * 128 + ub;
            asm volatile("global_store_dword %0, %1, off sc0 sc1"
                         :: "v"(fp), "v"(tgt) : "memory");
        }

        // kernel-exit-only stores: overlap next iteration
        if (kh == 0) {
            if (layer == 1) {
                float o0 = __shfl(hvA, bl),      o1 = __shfl(hvA, bl + 16);
                float o2 = __shfl(hvA, bl + 32), o3 = __shfl(hvA, bl + 48);
                float o4 = __shfl(hvB, bl),      o5 = __shfl(hvB, bl + 16);
                float o6 = __shfl(hvB, bl + 32), o7 = __shfl(hvB, bl + 48);
                if (lane < 16) {
                    float4 v0 = {o0, o1, o2, o3}, v1 = {o4, o5, o6, o7};
                    float* op = out + (size_t)t1 * 65536 + (size_t)(m * 16 + bl) * 1024 + u0g;
                    *(float4*)op = v0;
                    *(float4*)(op + 4) = v1;
                }
                if (t1 == TT - 1) {
                    int idx = (m * 16 + bl) * 1024 + u0g + ud;
                    out[OUT_HL + BH + idx] = hvA;  out[OUT_CL + BH + idx] = cnA;
                    out[OUT_HL + BH + idx + 4] = hvB;  out[OUT_CL + BH + idx + 4] = cnB;
                }
            } else if (s == TT - 1) {
                int idx = (m * 16 + bl) * 1024 + u0g + ud;
                out[OUT_HL + idx] = hvA;  out[OUT_CL + idx] = cnA;
                out[OUT_HL + idx + 4] = hvB;  out[OUT_CL + idx + 4] = cnB;
            }
        }
    }
}

extern "C" void kernel_launch(void* const* d_in, const int* in_sizes, int n_in,
                              void* d_out, int out_size, void* d_ws, size_t ws_size,
                              hipStream_t stream) {
    const float* attn = (const float*)d_in[0];
    const float* x    = (const float*)d_in[1];
    const float* h0   = (const float*)d_in[3];
    const float* c0   = (const float*)d_in[4];
    const float* wah  = (const float*)d_in[5];
    const float* wih  = (const float*)d_in[6];
    const float* whh  = (const float*)d_in[7];
    const float* bah  = (const float*)d_in[8];
    const float* bih  = (const float*)d_in[9];
    const float* bhh  = (const float*)d_in[10];
    float* out = (float*)d_out;

    char* ws = (char*)d_ws;
    ushort*   Wt     = (ushort*)(ws);               // [2][4096][2048] bf16 : 33,554,432
                                                    //   (first half reused as h1 ring)
    ushort*   xbfF   = (ushort*)(ws + 33554432);    // frag-major x     : 33,554,432
    ushort*   hs0F   = (ushort*)(ws + 67108864);    // [257] slots      : 33,685,504
    ushort*   h1s0   = (ushort*)(ws + 100794368);   // h1 ring slot 0   : 131,072
    float*    constg = (float*)(ws + 100925440);    // [2][64][4096]    : 2,097,152
    unsigned* flags  = (unsigned*)(ws + 103022592); // [256] u32 (f0|f1)
    // total 103,023,616 B

    hipLaunchKernelGGL(k_prep_wt, dim3(32, 64, 2), dim3(256), 0, stream, wih, whh, Wt);
    hipLaunchKernelGGL(k_cast_x, dim3(8192), dim3(256), 0, stream, x, xbfF);
    hipLaunchKernelGGL(k_const, dim3(16, 8, 2), dim3(256), 0, stream, attn, wah, bah, bih, bhh, constg);
    hipLaunchKernelGGL(k_init, dim3(64), dim3(256), 0, stream, h0, hs0F, h1s0, flags);

    void* args[] = { (void*)&xbfF, (void*)&hs0F, (void*)&h1s0, (void*)&Wt,
                     (void*)&constg, (void*)&c0, (void*)&out, (void*)&flags };
    hipLaunchCooperativeKernel((void*)k_persist, dim3(NBLK), dim3(512), args, 0, stream);
}

// Round 8
// 1786.877 us; speedup vs baseline: 1.1605x; 1.1605x over previous
//
#include <hip/hip_runtime.h>
#include <hip/hip_bf16.h>
#include <stdint.h>

// Problem constants
#define TT 256
#define BB 64
#define AA 512
#define II 1024
#define HH 1024
#define LL 2
// derived
#define BH 65536        // B*H
#define B4H 262144      // B*4H
#define OUT_HL 16777216
#define OUT_CL (16777216 + 131072)
#define NBLK 256

typedef __attribute__((ext_vector_type(8))) short bf16x8;
typedef __attribute__((ext_vector_type(4))) float f32x4;
typedef __attribute__((ext_vector_type(4))) unsigned int u32x4;
typedef __attribute__((ext_vector_type(2))) unsigned int u32x2;

__device__ __forceinline__ ushort f2bf(float v) {
    union { float f; uint32_t u; } x; x.f = v;
    uint32_t r = x.u + 0x7fff + ((x.u >> 16) & 1);
    return (ushort)(r >> 16);
}

__device__ __forceinline__ float sigf(float x) {   // 1/(1+e^-x), saturation-safe
    return 1.f / (1.f + __expf(-x));
}

// Fragment-major layout for [64][1024] bf16 activation slabs:
//   off(b,k) = (b>>4)*16384 + (k>>5)*512 + ((k>>3)&3)*128 + (b&15)*8 + (k&7)
// A wave loading m-tile m, k-tile kt reads 64 lanes x 16B CONTIGUOUS 1KB.

// Build Wt[l][col'][k] bf16, col' = u*4+g for source column col=g*1024+u.
// sc stores: region is later reused as the layer-1 h ring (plain cached reads).
__global__ __launch_bounds__(256) void k_prep_wt(const float* __restrict__ wih,
                                                 const float* __restrict__ whh,
                                                 ushort* __restrict__ Wt) {
    __shared__ ushort tile[64][65];
    const int l = blockIdx.z;
    const int k0 = blockIdx.x * 64;    // 0..2047
    const int col0 = blockIdx.y * 64;  // 0..4095
    const int tid = threadIdx.x;
    const int cl = tid & 63, ks = tid >> 6;
    const float* src;
    int krow0;
    if (k0 < 1024) { src = wih + (size_t)l * 1024 * 4096; krow0 = k0; }
    else           { src = whh + (size_t)l * 1024 * 4096; krow0 = k0 - 1024; }
#pragma unroll
    for (int i = 0; i < 16; ++i) {
        int kl = ks + i * 4;
        tile[kl][cl] = f2bf(src[(size_t)(krow0 + kl) * 4096 + col0 + cl]);
    }
    __syncthreads();
    const int g0 = col0 >> 10, ub = col0 & 1023;
    ushort* dst = Wt + (size_t)l * 4096 * 2048;
    const int klane = tid & 63;
#pragma unroll
    for (int i = 0; i < 16; ++i) {
        int cl2 = (tid >> 6) + i * 4;
        int row = (ub + cl2) * 4 + g0;
        ushort* p = dst + (size_t)row * 2048 + k0 + klane;
        uint v = (uint)tile[klane][cl2];
        asm volatile("global_store_short %0, %1, off sc0 sc1"
                     :: "v"(p), "v"(v) : "memory");
    }
}

// x -> bf16 fragment-major xbfF[t][...]
__global__ __launch_bounds__(256) void k_cast_x(const float* __restrict__ x,
                                                ushort* __restrict__ xbfF) {
    int i = blockIdx.x * 256 + threadIdx.x;   // [256 t][64 b][128 k8]
    int k8 = i & 127, b = (i >> 7) & 63, t = i >> 13;
    const float4* xs = (const float4*)(x + (((size_t)t * 64 + b) * 1024 + k8 * 8));
    float4 a = xs[0], c = xs[1];
    uint4 pk;
    pk.x = (uint)f2bf(a.x) | ((uint)f2bf(a.y) << 16);
    pk.y = (uint)f2bf(a.z) | ((uint)f2bf(a.w) << 16);
    pk.z = (uint)f2bf(c.x) | ((uint)f2bf(c.y) << 16);
    pk.w = (uint)f2bf(c.z) | ((uint)f2bf(c.w) << 16);
    size_t off = (size_t)t * 65536 + (size_t)(b >> 4) * 16384 +
                 (size_t)(k8 >> 2) * 512 + (size_t)(k8 & 3) * 128 + (size_t)(b & 15) * 8;
    *(uint4*)(xbfF + off) = pk;
}

// const[l][b][col] = a0[b,:] @ W_ah[l][:,col] + bias_ah + bias_ih + bias_hh
__global__ __launch_bounds__(256) void k_const(const float* __restrict__ attn,
                                               const float* __restrict__ wah,
                                               const float* __restrict__ bah,
                                               const float* __restrict__ bih,
                                               const float* __restrict__ bhh,
                                               float* __restrict__ constg) {
    const int tid = threadIdx.x;
    const int col = blockIdx.x * 256 + tid;
    const int b0 = blockIdx.y * 8;
    const int l = blockIdx.z;
    const float* W = wah + (size_t)l * 512 * 4096;
    float acc[8] = {0.f, 0.f, 0.f, 0.f, 0.f, 0.f, 0.f, 0.f};
    for (int k = 0; k < 512; ++k) {
        float wv = W[(size_t)k * 4096 + col];
#pragma unroll
        for (int j = 0; j < 8; ++j) acc[j] += attn[(b0 + j) * 512 + k] * wv;
    }
    float bias = bah[l * 4096 + col] + bih[l * 4096 + col] + bhh[l * 4096 + col];
    float* cg = constg + (size_t)l * B4H;
#pragma unroll
    for (int j = 0; j < 8; ++j) cg[(size_t)(b0 + j) * 4096 + col] = acc[j] + bias;
}

// h0 -> fragment-major initial slots
__global__ __launch_bounds__(256) void k_init(const float* __restrict__ h0,
                                              ushort* __restrict__ hs0F,
                                              ushort* __restrict__ h1s0,
                                              unsigned* __restrict__ flags) {
    int i = blockIdx.x * 256 + threadIdx.x;   // [2 l][64 b][128 k8] = 16384
    if (i < 16384) {
        int k8 = i & 127, b = (i >> 7) & 63, l = i >> 13;
        const float* src = h0 + ((size_t)(l * 64 + b) * 1024 + k8 * 8);
        uint4 pk;
        pk.x = (uint)f2bf(src[0]) | ((uint)f2bf(src[1]) << 16);
        pk.y = (uint)f2bf(src[2]) | ((uint)f2bf(src[3]) << 16);
        pk.z = (uint)f2bf(src[4]) | ((uint)f2bf(src[5]) << 16);
        pk.w = (uint)f2bf(src[6]) | ((uint)f2bf(src[7]) << 16);
        size_t off = (size_t)(b >> 4) * 16384 + (size_t)(k8 >> 2) * 512 +
                     (size_t)(k8 & 3) * 128 + (size_t)(b & 15) * 8;
        *(uint4*)((l == 0 ? hs0F : h1s0) + off) = pk;
    }
    if (i < NBLK) flags[i] = 0u;
}

// ---- inline-asm helpers ----
#define ISSUE(BUF, BASE)                                                       \
    do {                                                                       \
        _Pragma("unroll")                                                      \
        for (int _i = 0; _i < 8; ++_i)                                         \
            asm volatile("global_load_dwordx4 %0, %1, off"                     \
                         : "=v"(BUF[_i]) : "v"((BASE) + _i * 512));            \
    } while (0)

// Wait (N outstanding allowed), then 8 A-frags x 2 n-tiles = 16 MFMAs.
#define CONSUME2(BUF, c, N, A0, A1)                                            \
    do {                                                                       \
        asm volatile("s_waitcnt vmcnt(" #N ")" ::: "memory");                  \
        __builtin_amdgcn_sched_barrier(0x100);                                 \
        _Pragma("unroll")                                                      \
        for (int _i = 0; _i < 8; ++_i) {                                       \
            int _ktg = kh * 32 + (c) * 8 + _i;                                 \
            bf16x8 _b0 = *(const bf16x8*)(wlds + (size_t)_ktg * 1024 + lane * 8);       \
            bf16x8 _b1 = *(const bf16x8*)(wlds + (size_t)_ktg * 1024 + 512 + lane * 8); \
            A0 = __builtin_amdgcn_mfma_f32_16x16x32_bf16(BUF[_i], _b0, A0, 0, 0, 0);    \
            A1 = __builtin_amdgcn_mfma_f32_16x16x32_bf16(BUF[_i], _b1, A1, 0, 0, 0);    \
        }                                                                      \
    } while (0)

#define LOADCOMPUTE(AL)                                                        \
    do {                                                                       \
        const ushort* _a = (AL);                                               \
        ISSUE(bufA, _a + 0 * 4096);                                            \
        ISSUE(bufB, _a + 1 * 4096);                                            \
        ISSUE(bufC, _a + 2 * 4096);                                            \
        ISSUE(bufD, _a + 3 * 4096);                                            \
        CONSUME2(bufA, 0, 24, aE0, aE1);                                       \
        CONSUME2(bufB, 1, 16, aO0, aO1);                                       \
        CONSUME2(bufC, 2, 8,  aE0, aE1);                                       \
        CONSUME2(bufD, 3, 0,  aO0, aO1);                                       \
        const int _cc = lane & 15, _r0 = (lane >> 4) * 4;                      \
        _Pragma("unroll")                                                      \
        for (int _r = 0; _r < 4; ++_r) {                                       \
            gt[kh][m][0][_r0 + _r][_cc] = aE0[_r] + aO0[_r];                   \
            gt[kh][m][1][_r0 + _r][_cc] = aE1[_r] + aO1[_r];                   \
        }                                                                      \
    } while (0)

// 128-flag poll, single wave, 2 flags/lane.
#define POLL128(FB, TGT)                                                       \
    do {                                                                       \
        const unsigned* _fp = (FB) + lane * 2;                                 \
        while (true) {                                                         \
            u32x2 _f;                                                          \
            asm volatile("global_load_dwordx2 %0, %1, off sc0 sc1\n\t"         \
                         "s_waitcnt vmcnt(0)"                                  \
                         : "=v"(_f) : "v"(_fp) : "memory");                    \
            if (__all(_f.x >= (TGT) && _f.y >= (TGT))) break;                  \
            __builtin_amdgcn_s_sleep(1);                                       \
        }                                                                      \
    } while (0)

// Persistent 2-layer LSTM, layer-split: blocks 0-127 = layer0 (8 units each),
// blocks 128-255 = layer1. Waves 0-3 k-half 0, waves 4-7 k-half 1; partial
// sums meet in gt; epilogue balanced over all 512 threads (1 cell each).
// ONE polling wave per block (w0). Layer1: two-phase poll (f0 -> f1) so the
// hs0F ingest overlaps the f1 wait. Flags: f0[128], f1[128]; store s+1.
__global__ __launch_bounds__(512, 2) void k_persist(
        const ushort* __restrict__ xbfF,
        ushort* __restrict__ hs0F,
        const ushort* __restrict__ h1s0,
        ushort* Wt,                       // staging source + h1 ring (aliased)
        const float* __restrict__ constg,
        const float* __restrict__ c0,
        float* __restrict__ out,
        unsigned* __restrict__ flags) {
    __shared__ ushort wlds[65536];          // [64 ktg][2 nt][64 lane][8] = 128 KiB
    __shared__ float gt[2][4][2][16][18];   // [kh][m][nt][b&15][col'] 18 KiB

    const int tid = threadIdx.x;
    const int w = tid >> 6, lane = tid & 63;
    const int kh = w >> 2, m = w & 3;
    const int bid = blockIdx.x;
    const int layer = bid >> 7, ub = bid & 127;
    const int u0g = ub * 8;

    // ---- stage this layer's 32 gate-cols x 2048 k into LDS (sc loads) ----
    {
        bf16x8 vst[16];
#pragma unroll
        for (int i = 0; i < 16; ++i) {
            int c = i * 512 + tid;          // 0..8191 chunks of 16B
            int lp = c & 63, nt = (c >> 6) & 1, ktg = c >> 7;
            int colp = u0g * 4 + nt * 16 + (lp & 15);
            int kk = ktg * 32 + (lp >> 4) * 8;
            const ushort* src = Wt + ((size_t)(layer * 4096 + colp)) * 2048 + kk;
            asm volatile("global_load_dwordx4 %0, %1, off sc0 sc1"
                         : "=v"(vst[i]) : "v"(src));
        }
        asm volatile("s_waitcnt vmcnt(0)" ::: "memory");
        __builtin_amdgcn_sched_barrier(0);
#pragma unroll
        for (int i = 0; i < 16; ++i) {
            int c = i * 512 + tid;
            *(bf16x8*)(wlds + (size_t)c * 8) = vst[i];
        }
    }

    // ---- per-thread epilogue cell: b_e = w*8 + lane/8, u_e = u0g + lane%8 ----
    const int b_e = (w << 3) | (lane >> 3);
    const int u_off = lane & 7;
    const int u_e = u0g + u_off;
    float cg[4];
#pragma unroll
    for (int g = 0; g < 4; ++g)
        cg[g] = constg[(size_t)layer * B4H + (size_t)b_e * 4096 + g * 1024 + u_e];
    float creg = c0[layer * BH + b_e * 1024 + u_e];
    const int mb = b_e >> 4, blb = b_e & 15, ntb = u_off >> 2, cpb = (u_off & 3) * 4;
    const size_t hoffL = (size_t)(b_e >> 4) * 16384 + (size_t)(ub >> 2) * 512 +
                         (size_t)(ub & 3) * 128 + (size_t)(b_e & 15) * 8;

    const size_t fro = (size_t)m * 16384 + (size_t)lane * 8;

    __syncthreads();

    const int sBeg = layer ? 1 : 0;
    const int sEnd = layer ? TT : (TT - 1);
    for (int s = sBeg; s <= sEnd; ++s) {
        const int t1 = s - 1;
        bf16x8 bufA[8], bufB[8], bufC[8], bufD[8];
        f32x4 aE0 = {0.f,0.f,0.f,0.f}, aO0 = {0.f,0.f,0.f,0.f};
        f32x4 aE1 = {0.f,0.f,0.f,0.f}, aO1 = {0.f,0.f,0.f,0.f};

        if (layer == 0) {
            // kh0: static x half, fully pre-poll (loads completed inside).
            if (kh == 0) LOADCOMPUTE(xbfF + (size_t)s * 65536 + fro);
            if (s >= 1 && w == 0) POLL128(flags, (unsigned)s);
            __syncthreads();                          // release
            if (kh == 1) LOADCOMPUTE(hs0F + (size_t)s * 65536 + fro);
        } else {
            if (w == 0) POLL128(flags, (unsigned)s);  // f0 >= s
            __syncthreads();                          // sync_a
            if (kh == 0 && w != 0)
                LOADCOMPUTE(hs0F + (size_t)s * 65536 + fro);
            if (w == 0 && s >= 2) POLL128(flags + 128, (unsigned)s);  // f1 >= s
            __syncthreads();                          // sync_b
            if (kh == 1) {
                const ushort* Al = (t1 == 0 ? h1s0
                                   : (const ushort*)Wt + (size_t)(t1 - 1) * 65536) + fro;
                LOADCOMPUTE(Al);
            } else if (w == 0) {
                LOADCOMPUTE(hs0F + (size_t)s * 65536 + fro);
            }
        }
        __syncthreads();                              // sync1: partials visible

        // ---- balanced epilogue: every thread one (b_e, u_e) cell ----
        float g4[4];
#pragma unroll
        for (int g = 0; g < 4; ++g)
            g4[g] = gt[0][mb][ntb][blb][cpb + g] + gt[1][mb][ntb][blb][cpb + g] + cg[g];
        float si = sigf(g4[0]), sf = sigf(g4[1]), so = sigf(g4[3]);
        float cn = sf * creg + si * (2.f * sigf(2.f * g4[2]) - 1.f);
        float hv = so * (2.f * sigf(2.f * cn) - 1.f);
        creg = cn;
        uint hb = (uint)f2bf(hv);
        uint p0 = __shfl(hb, (lane & 56) + 0), p1 = __shfl(hb, (lane & 56) + 1);
        uint p2 = __shfl(hb, (lane & 56) + 2), p3 = __shfl(hb, (lane & 56) + 3);
        uint p4 = __shfl(hb, (lane & 56) + 4), p5 = __shfl(hb, (lane & 56) + 5);
        uint p6 = __shfl(hb, (lane & 56) + 6), p7 = __shfl(hb, (lane & 56) + 7);
        u32x4 hp;
        hp.x = (p0 & 0xffffu) | (p1 << 16);
        hp.y = (p2 & 0xffffu) | (p3 << 16);
        hp.z = (p4 & 0xffffu) | (p5 << 16);
        hp.w = (p6 & 0xffffu) | (p7 << 16);
        ushort* hdst = (layer ? Wt + (size_t)t1 * 65536
                              : hs0F + (size_t)(s + 1) * 65536) + hoffL;
        if (u_off == 0)
            asm volatile("global_store_dwordx4 %0, %1, off sc0 sc1"
                         :: "v"(hdst), "v"(hp) : "memory");

        // drain h-stores, block barrier, signal own flag
        asm volatile("s_waitcnt vmcnt(0)" ::: "memory");
        __syncthreads();                              // sync2
        if (tid == 0) {
            unsigned tgt = (unsigned)(s + 1);
            unsigned* fp = flags + layer * 128 + ub;
            asm volatile("global_store_dword %0, %1, off sc0 sc1"
                         :: "v"(fp), "v"(tgt) : "memory");
        }

        // kernel-exit-only stores: overlap next iteration
        if (layer == 1) {
            float o0 = __shfl(hv, (lane & 56) + 0), o1 = __shfl(hv, (lane & 56) + 1);
            float o2 = __shfl(hv, (lane & 56) + 2), o3 = __shfl(hv, (lane & 56) + 3);
            float o4 = __shfl(hv, (lane & 56) + 4), o5 = __shfl(hv, (lane & 56) + 5);
            float o6 = __shfl(hv, (lane & 56) + 6), o7 = __shfl(hv, (lane & 56) + 7);
            if (u_off == 0) {
                float* op = out + (size_t)t1 * 65536 + (size_t)b_e * 1024 + u0g;
                float4 v0 = {o0, o1, o2, o3}, v1 = {o4, o5, o6, o7};
                *(float4*)op = v0;
                *(float4*)(op + 4) = v1;
            }
            if (t1 == TT - 1) {
                out[OUT_HL + BH + b_e * 1024 + u_e] = hv;
                out[OUT_CL + BH + b_e * 1024 + u_e] = cn;
            }
        } else if (s == TT - 1) {
            out[OUT_HL + b_e * 1024 + u_e] = hv;
            out[OUT_CL + b_e * 1024 + u_e] = cn;
        }
    }
}

extern "C" void kernel_launch(void* const* d_in, const int* in_sizes, int n_in,
                              void* d_out, int out_size, void* d_ws, size_t ws_size,
                              hipStream_t stream) {
    const float* attn = (const float*)d_in[0];
    const float* x    = (const float*)d_in[1];
    const float* h0   = (const float*)d_in[3];
    const float* c0   = (const float*)d_in[4];
    const float* wah  = (const float*)d_in[5];
    const float* wih  = (const float*)d_in[6];
    const float* whh  = (const float*)d_in[7];
    const float* bah  = (const float*)d_in[8];
    const float* bih  = (const float*)d_in[9];
    const float* bhh  = (const float*)d_in[10];
    float* out = (float*)d_out;

    char* ws = (char*)d_ws;
    ushort*   Wt     = (ushort*)(ws);               // [2][4096][2048] bf16 : 33,554,432
                                                    //   (reused as h1 ring, slots 0..255)
    ushort*   xbfF   = (ushort*)(ws + 33554432);    // frag-major x     : 33,554,432
    ushort*   hs0F   = (ushort*)(ws + 67108864);    // [257] slots      : 33,685,504
    ushort*   h1s0   = (ushort*)(ws + 100794368);   // h1 ring slot 0   : 131,072
    float*    constg = (float*)(ws + 100925440);    // [2][64][4096]    : 2,097,152
    unsigned* flags  = (unsigned*)(ws + 103022592); // [256] u32 (f0|f1)
    // total 103,023,616 B

    hipLaunchKernelGGL(k_prep_wt, dim3(32, 64, 2), dim3(256), 0, stream, wih, whh, Wt);
    hipLaunchKernelGGL(k_cast_x, dim3(8192), dim3(256), 0, stream, x, xbfF);
    hipLaunchKernelGGL(k_const, dim3(16, 8, 2), dim3(256), 0, stream, attn, wah, bah, bih, bhh, constg);
    hipLaunchKernelGGL(k_init, dim3(64), dim3(256), 0, stream, h0, hs0F, h1s0, flags);

    void* args[] = { (void*)&xbfF, (void*)&hs0F, (void*)&h1s0, (void*)&Wt,
                     (void*)&constg, (void*)&c0, (void*)&out, (void*)&flags };
    hipLaunchCooperativeKernel((void*)k_persist, dim3(NBLK), dim3(512), args, 0, stream);
}

// Round 9
// 1680.617 us; speedup vs baseline: 1.2339x; 1.0632x over previous
//
#include <hip/hip_runtime.h>
#include <hip/hip_bf16.h>
#include <stdint.h>

// Problem constants
#define TT 256
#define BB 64
#define AA 512
#define II 1024
#define HH 1024
#define LL 2
// derived
#define BH 65536        // B*H
#define B4H 262144      // B*4H
#define OUT_HL 16777216
#define OUT_CL (16777216 + 131072)
#define NBLK 256

typedef __attribute__((ext_vector_type(8))) short bf16x8;
typedef __attribute__((ext_vector_type(4))) float f32x4;
typedef __attribute__((ext_vector_type(4))) unsigned int u32x4;
typedef __attribute__((ext_vector_type(2))) unsigned int u32x2;

__device__ __forceinline__ ushort f2bf(float v) {
    union { float f; uint32_t u; } x; x.f = v;
    uint32_t r = x.u + 0x7fff + ((x.u >> 16) & 1);
    return (ushort)(r >> 16);
}

__device__ __forceinline__ float sigf(float x) {   // 1/(1+e^-x), saturation-safe
    return 1.f / (1.f + __expf(-x));
}

// Fragment-major layout for [64][1024] bf16 activation slabs:
//   off(b,k) = (b>>4)*16384 + (k>>5)*512 + ((k>>3)&3)*128 + (b&15)*8 + (k&7)
// A wave loading m-tile m, k-group ktg reads 64 lanes x 16B CONTIGUOUS 1KB.

// Build Wt[l][col'][k] bf16, col' = u*4+g for source column col=g*1024+u.
// sc stores: region is later reused as the layer-1 h ring (plain cached reads).
__global__ __launch_bounds__(256) void k_prep_wt(const float* __restrict__ wih,
                                                 const float* __restrict__ whh,
                                                 ushort* __restrict__ Wt) {
    __shared__ ushort tile[64][65];
    const int l = blockIdx.z;
    const int k0 = blockIdx.x * 64;    // 0..2047
    const int col0 = blockIdx.y * 64;  // 0..4095
    const int tid = threadIdx.x;
    const int cl = tid & 63, ks = tid >> 6;
    const float* src;
    int krow0;
    if (k0 < 1024) { src = wih + (size_t)l * 1024 * 4096; krow0 = k0; }
    else           { src = whh + (size_t)l * 1024 * 4096; krow0 = k0 - 1024; }
#pragma unroll
    for (int i = 0; i < 16; ++i) {
        int kl = ks + i * 4;
        tile[kl][cl] = f2bf(src[(size_t)(krow0 + kl) * 4096 + col0 + cl]);
    }
    __syncthreads();
    const int g0 = col0 >> 10, ub = col0 & 1023;
    ushort* dst = Wt + (size_t)l * 4096 * 2048;
    const int klane = tid & 63;
#pragma unroll
    for (int i = 0; i < 16; ++i) {
        int cl2 = (tid >> 6) + i * 4;
        int row = (ub + cl2) * 4 + g0;
        ushort* p = dst + (size_t)row * 2048 + k0 + klane;
        uint v = (uint)tile[klane][cl2];
        asm volatile("global_store_short %0, %1, off sc0 sc1"
                     :: "v"(p), "v"(v) : "memory");
    }
}

// x -> bf16 fragment-major xbfF[t][...]
__global__ __launch_bounds__(256) void k_cast_x(const float* __restrict__ x,
                                                ushort* __restrict__ xbfF) {
    int i = blockIdx.x * 256 + threadIdx.x;   // [256 t][64 b][128 k8]
    int k8 = i & 127, b = (i >> 7) & 63, t = i >> 13;
    const float4* xs = (const float4*)(x + (((size_t)t * 64 + b) * 1024 + k8 * 8));
    float4 a = xs[0], c = xs[1];
    uint4 pk;
    pk.x = (uint)f2bf(a.x) | ((uint)f2bf(a.y) << 16);
    pk.y = (uint)f2bf(a.z) | ((uint)f2bf(a.w) << 16);
    pk.z = (uint)f2bf(c.x) | ((uint)f2bf(c.y) << 16);
    pk.w = (uint)f2bf(c.z) | ((uint)f2bf(c.w) << 16);
    size_t off = (size_t)t * 65536 + (size_t)(b >> 4) * 16384 +
                 (size_t)(k8 >> 2) * 512 + (size_t)(k8 & 3) * 128 + (size_t)(b & 15) * 8;
    *(uint4*)(xbfF + off) = pk;
}

// const[l][b][col] = a0[b,:] @ W_ah[l][:,col] + bias_ah + bias_ih + bias_hh
__global__ __launch_bounds__(256) void k_const(const float* __restrict__ attn,
                                               const float* __restrict__ wah,
                                               const float* __restrict__ bah,
                                               const float* __restrict__ bih,
                                               const float* __restrict__ bhh,
                                               float* __restrict__ constg) {
    const int tid = threadIdx.x;
    const int col = blockIdx.x * 256 + tid;
    const int b0 = blockIdx.y * 8;
    const int l = blockIdx.z;
    const float* W = wah + (size_t)l * 512 * 4096;
    float acc[8] = {0.f, 0.f, 0.f, 0.f, 0.f, 0.f, 0.f, 0.f};
    for (int k = 0; k < 512; ++k) {
        float wv = W[(size_t)k * 4096 + col];
#pragma unroll
        for (int j = 0; j < 8; ++j) acc[j] += attn[(b0 + j) * 512 + k] * wv;
    }
    float bias = bah[l * 4096 + col] + bih[l * 4096 + col] + bhh[l * 4096 + col];
    float* cg = constg + (size_t)l * B4H;
#pragma unroll
    for (int j = 0; j < 8; ++j) cg[(size_t)(b0 + j) * 4096 + col] = acc[j] + bias;
}

// h0 -> fragment-major initial slots
__global__ __launch_bounds__(256) void k_init(const float* __restrict__ h0,
                                              ushort* __restrict__ hs0F,
                                              ushort* __restrict__ h1s0,
                                              unsigned* __restrict__ flags) {
    int i = blockIdx.x * 256 + threadIdx.x;   // [2 l][64 b][128 k8] = 16384
    if (i < 16384) {
        int k8 = i & 127, b = (i >> 7) & 63, l = i >> 13;
        const float* src = h0 + ((size_t)(l * 64 + b) * 1024 + k8 * 8);
        uint4 pk;
        pk.x = (uint)f2bf(src[0]) | ((uint)f2bf(src[1]) << 16);
        pk.y = (uint)f2bf(src[2]) | ((uint)f2bf(src[3]) << 16);
        pk.z = (uint)f2bf(src[4]) | ((uint)f2bf(src[5]) << 16);
        pk.w = (uint)f2bf(src[6]) | ((uint)f2bf(src[7]) << 16);
        size_t off = (size_t)(b >> 4) * 16384 + (size_t)(k8 >> 2) * 512 +
                     (size_t)(k8 & 3) * 128 + (size_t)(b & 15) * 8;
        *(uint4*)((l == 0 ? hs0F : h1s0) + off) = pk;
    }
    if (i < NBLK) flags[i] = 0u;
}

// ---- inline-asm helpers ----
// 8 x 16B fragment loads, stride 1KB.
#define ISSUE(BUF, BASE)                                                       \
    do {                                                                       \
        _Pragma("unroll")                                                      \
        for (int _i = 0; _i < 8; ++_i)                                         \
            asm volatile("global_load_dwordx4 %0, %1, off"                     \
                         : "=v"(BUF[_i]) : "v"((BASE) + _i * 512));            \
    } while (0)

// Wait (N outstanding allowed), then 8 A-frags x 2 n-tiles = 16 MFMAs.
#define CHUNK(BUF, KTG0, N, A0, A1)                                            \
    do {                                                                       \
        asm volatile("s_waitcnt vmcnt(" #N ")" ::: "memory");                  \
        __builtin_amdgcn_sched_barrier(0x100);                                 \
        _Pragma("unroll")                                                      \
        for (int _i = 0; _i < 8; ++_i) {                                       \
            int _ktg = (KTG0) + _i;                                            \
            bf16x8 _b0 = *(const bf16x8*)(wlds + (size_t)_ktg * 1024 + lane * 8);       \
            bf16x8 _b1 = *(const bf16x8*)(wlds + (size_t)_ktg * 1024 + 512 + lane * 8); \
            A0 = __builtin_amdgcn_mfma_f32_16x16x32_bf16(BUF[_i], _b0, A0, 0, 0, 0);    \
            A1 = __builtin_amdgcn_mfma_f32_16x16x32_bf16(BUF[_i], _b1, A1, 0, 0, 0);    \
        }                                                                      \
    } while (0)

// 128-flag poll, single wave, 2 flags/lane.
#define POLL128(FB, TGT)                                                       \
    do {                                                                       \
        const unsigned* _fp = (FB) + lane * 2;                                 \
        while (true) {                                                         \
            u32x2 _f;                                                          \
            asm volatile("global_load_dwordx2 %0, %1, off sc0 sc1\n\t"         \
                         "s_waitcnt vmcnt(0)"                                  \
                         : "=v"(_f) : "v"(_fp) : "memory");                    \
            if (__all(_f.x >= (TGT) && _f.y >= (TGT))) break;                  \
            __builtin_amdgcn_s_sleep(1);                                       \
        }                                                                      \
    } while (0)

// Persistent 2-layer LSTM, layer-split: blocks 0-127 = layer0 (8 units each),
// blocks 128-255 = layer1.
// Layer0: pre-poll, ALL 8 waves compute half the x-half each (16 ktg); w0
// polls f0; post-poll, all 8 waves compute half the h-half each (16 ktg).
// Layer1: w0 polls f0 WHILE w4 polls f1 (concurrent); one sync releases;
// kh0 waves ingest hs0F (ktg 0..31), kh1 waves ingest the ring (ktg 32..63).
// Partial sums meet in gt; epilogue balanced over all 512 threads.
// Flags: f0[128], f1[128]; store s+1 at end of iter s.
__global__ __launch_bounds__(512, 2) void k_persist(
        const ushort* __restrict__ xbfF,
        ushort* __restrict__ hs0F,
        const ushort* __restrict__ h1s0,
        ushort* Wt,                       // staging source + h1 ring (aliased)
        const float* __restrict__ constg,
        const float* __restrict__ c0,
        float* __restrict__ out,
        unsigned* __restrict__ flags) {
    __shared__ ushort wlds[65536];          // [64 ktg][2 nt][64 lane][8] = 128 KiB
    __shared__ float gt[2][4][2][16][18];   // [kh][m][nt][b&15][col'] 18 KiB

    const int tid = threadIdx.x;
    const int w = tid >> 6, lane = tid & 63;
    const int kh = w >> 2, m = w & 3;
    const int bid = blockIdx.x;
    const int layer = bid >> 7, ub = bid & 127;
    const int u0g = ub * 8;

    // ---- stage this layer's 32 gate-cols x 2048 k into LDS (sc loads) ----
    {
        bf16x8 vst[16];
#pragma unroll
        for (int i = 0; i < 16; ++i) {
            int c = i * 512 + tid;          // 0..8191 chunks of 16B
            int lp = c & 63, nt = (c >> 6) & 1, ktg = c >> 7;
            int colp = u0g * 4 + nt * 16 + (lp & 15);
            int kk = ktg * 32 + (lp >> 4) * 8;
            const ushort* src = Wt + ((size_t)(layer * 4096 + colp)) * 2048 + kk;
            asm volatile("global_load_dwordx4 %0, %1, off sc0 sc1"
                         : "=v"(vst[i]) : "v"(src));
        }
        asm volatile("s_waitcnt vmcnt(0)" ::: "memory");
        __builtin_amdgcn_sched_barrier(0);
#pragma unroll
        for (int i = 0; i < 16; ++i) {
            int c = i * 512 + tid;
            *(bf16x8*)(wlds + (size_t)c * 8) = vst[i];
        }
    }

    // ---- per-thread epilogue cell: b_e = w*8 + lane/8, u_e = u0g + lane%8 ----
    const int b_e = (w << 3) | (lane >> 3);
    const int u_off = lane & 7;
    const int u_e = u0g + u_off;
    float cg[4];
#pragma unroll
    for (int g = 0; g < 4; ++g)
        cg[g] = constg[(size_t)layer * B4H + (size_t)b_e * 4096 + g * 1024 + u_e];
    float creg = c0[layer * BH + b_e * 1024 + u_e];
    const int mb = b_e >> 4, blb = b_e & 15, ntb = u_off >> 2, cpb = (u_off & 3) * 4;
    const size_t hoffL = (size_t)mb * 16384 + (size_t)(ub >> 2) * 512 +
                         (size_t)(ub & 3) * 128 + (size_t)blb * 8;

    const size_t fro = (size_t)m * 16384 + (size_t)lane * 8;

    __syncthreads();

    const int sBeg = layer ? 1 : 0;
    const int sEnd = layer ? TT : (TT - 1);
    for (int s = sBeg; s <= sEnd; ++s) {
        const int t1 = s - 1;
        bf16x8 bufA[8], bufB[8], bufC[8], bufD[8];
        f32x4 aE0 = {0.f,0.f,0.f,0.f}, aO0 = {0.f,0.f,0.f,0.f};
        f32x4 aE1 = {0.f,0.f,0.f,0.f}, aO1 = {0.f,0.f,0.f,0.f};

        if (layer == 0) {
            // pre-poll: every wave computes 16 ktg of the static x half,
            // fully completed before the poll (no in-flight asm regs).
            {
                const ushort* ax = xbfF + (size_t)s * 65536 + fro + kh * 8192;
                ISSUE(bufA, ax);
                ISSUE(bufB, ax + 4096);
                CHUNK(bufA, kh * 16,     8, aE0, aE1);
                CHUNK(bufB, kh * 16 + 8, 0, aO0, aO1);
            }
            if (s >= 1 && w == 0) POLL128(flags, (unsigned)s);
            __syncthreads();
            // post-poll: every wave computes 16 ktg of the h half.
            {
                const ushort* ah = hs0F + (size_t)s * 65536 + fro + kh * 8192;
                ISSUE(bufA, ah);
                ISSUE(bufB, ah + 4096);
                CHUNK(bufA, 32 + kh * 16,     8, aE0, aE1);
                CHUNK(bufB, 32 + kh * 16 + 8, 0, aO0, aO1);
            }
        } else {
            // concurrent polls: w0 waits f0>=s, w4 waits f1>=s.
            if (w == 0) POLL128(flags, (unsigned)s);
            if (w == 4 && s >= 2) POLL128(flags + 128, (unsigned)s);
            __syncthreads();
            // kh0 waves: hs0F slab (ktg 0..31); kh1 waves: ring (ktg 32..63).
            {
                const ushort* a = (kh == 0)
                    ? hs0F + (size_t)s * 65536 + fro
                    : (t1 == 0 ? h1s0 + fro
                               : (const ushort*)Wt + (size_t)(t1 - 1) * 65536 + fro);
                ISSUE(bufA, a);
                ISSUE(bufB, a + 4096);
                ISSUE(bufC, a + 8192);
                ISSUE(bufD, a + 12288);
                CHUNK(bufA, kh * 32,      24, aE0, aE1);
                CHUNK(bufB, kh * 32 + 8,  16, aO0, aO1);
                CHUNK(bufC, kh * 32 + 16,  8, aE0, aE1);
                CHUNK(bufD, kh * 32 + 24,  0, aO0, aO1);
            }
        }

        // partial gates -> gt  (C/D map: col = lane&15, row = (lane>>4)*4 + r)
        {
            const int cc = lane & 15, r0 = (lane >> 4) * 4;
#pragma unroll
            for (int r = 0; r < 4; ++r) {
                gt[kh][m][0][r0 + r][cc] = aE0[r] + aO0[r];
                gt[kh][m][1][r0 + r][cc] = aE1[r] + aO1[r];
            }
        }
        __syncthreads();                              // sync1: partials visible

        // ---- balanced epilogue: every thread one (b_e, u_e) cell ----
        float g4[4];
#pragma unroll
        for (int g = 0; g < 4; ++g)
            g4[g] = gt[0][mb][ntb][blb][cpb + g] + gt[1][mb][ntb][blb][cpb + g] + cg[g];
        float si = sigf(g4[0]), sf = sigf(g4[1]), so = sigf(g4[3]);
        float cn = sf * creg + si * (2.f * sigf(2.f * g4[2]) - 1.f);
        float hv = so * (2.f * sigf(2.f * cn) - 1.f);
        creg = cn;
        uint hb = (uint)f2bf(hv);
        uint p0 = __shfl(hb, (lane & 56) + 0), p1 = __shfl(hb, (lane & 56) + 1);
        uint p2 = __shfl(hb, (lane & 56) + 2), p3 = __shfl(hb, (lane & 56) + 3);
        uint p4 = __shfl(hb, (lane & 56) + 4), p5 = __shfl(hb, (lane & 56) + 5);
        uint p6 = __shfl(hb, (lane & 56) + 6), p7 = __shfl(hb, (lane & 56) + 7);
        u32x4 hp;
        hp.x = (p0 & 0xffffu) | (p1 << 16);
        hp.y = (p2 & 0xffffu) | (p3 << 16);
        hp.z = (p4 & 0xffffu) | (p5 << 16);
        hp.w = (p6 & 0xffffu) | (p7 << 16);
        ushort* hdst = (layer ? Wt + (size_t)t1 * 65536
                              : hs0F + (size_t)(s + 1) * 65536) + hoffL;
        if (u_off == 0)
            asm volatile("global_store_dwordx4 %0, %1, off sc0 sc1"
                         :: "v"(hdst), "v"(hp) : "memory");

        // drain h-stores, block barrier, signal own flag
        asm volatile("s_waitcnt vmcnt(0)" ::: "memory");
        __syncthreads();                              // sync2
        if (tid == 0) {
            unsigned tgt = (unsigned)(s + 1);
            unsigned* fp = flags + layer * 128 + ub;
            asm volatile("global_store_dword %0, %1, off sc0 sc1"
                         :: "v"(fp), "v"(tgt) : "memory");
        }

        // kernel-exit-only stores: overlap next iteration
        if (layer == 1) {
            float o0 = __shfl(hv, (lane & 56) + 0), o1 = __shfl(hv, (lane & 56) + 1);
            float o2 = __shfl(hv, (lane & 56) + 2), o3 = __shfl(hv, (lane & 56) + 3);
            float o4 = __shfl(hv, (lane & 56) + 4), o5 = __shfl(hv, (lane & 56) + 5);
            float o6 = __shfl(hv, (lane & 56) + 6), o7 = __shfl(hv, (lane & 56) + 7);
            if (u_off == 0) {
                float* op = out + (size_t)t1 * 65536 + (size_t)b_e * 1024 + u0g;
                float4 v0 = {o0, o1, o2, o3}, v1 = {o4, o5, o6, o7};
                *(float4*)op = v0;
                *(float4*)(op + 4) = v1;
            }
            if (t1 == TT - 1) {
                out[OUT_HL + BH + b_e * 1024 + u_e] = hv;
                out[OUT_CL + BH + b_e * 1024 + u_e] = cn;
            }
        } else if (s == TT - 1) {
            out[OUT_HL + b_e * 1024 + u_e] = hv;
            out[OUT_CL + b_e * 1024 + u_e] = cn;
        }
    }
}

extern "C" void kernel_launch(void* const* d_in, const int* in_sizes, int n_in,
                              void* d_out, int out_size, void* d_ws, size_t ws_size,
                              hipStream_t stream) {
    const float* attn = (const float*)d_in[0];
    const float* x    = (const float*)d_in[1];
    const float* h0   = (const float*)d_in[3];
    const float* c0   = (const float*)d_in[4];
    const float* wah  = (const float*)d_in[5];
    const float* wih  = (const float*)d_in[6];
    const float* whh  = (const float*)d_in[7];
    const float* bah  = (const float*)d_in[8];
    const float* bih  = (const float*)d_in[9];
    const float* bhh  = (const float*)d_in[10];
    float* out = (float*)d_out;

    char* ws = (char*)d_ws;
    ushort*   Wt     = (ushort*)(ws);               // [2][4096][2048] bf16 : 33,554,432
                                                    //   (reused as h1 ring, slots 0..255)
    ushort*   xbfF   = (ushort*)(ws + 33554432);    // frag-major x     : 33,554,432
    ushort*   hs0F   = (ushort*)(ws + 67108864);    // [257] slots      : 33,685,504
    ushort*   h1s0   = (ushort*)(ws + 100794368);   // h1 ring slot 0   : 131,072
    float*    constg = (float*)(ws + 100925440);    // [2][64][4096]    : 2,097,152
    unsigned* flags  = (unsigned*)(ws + 103022592); // [256] u32 (f0|f1)
    // total 103,023,616 B

    hipLaunchKernelGGL(k_prep_wt, dim3(32, 64, 2), dim3(256), 0, stream, wih, whh, Wt);
    hipLaunchKernelGGL(k_cast_x, dim3(8192), dim3(256), 0, stream, x, xbfF);
    hipLaunchKernelGGL(k_const, dim3(16, 8, 2), dim3(256), 0, stream, attn, wah, bah, bih, bhh, constg);
    hipLaunchKernelGGL(k_init, dim3(64), dim3(256), 0, stream, h0, hs0F, h1s0, flags);

    void* args[] = { (void*)&xbfF, (void*)&hs0F, (void*)&h1s0, (void*)&Wt,
                     (void*)&constg, (void*)&c0, (void*)&out, (void*)&flags };
    hipLaunchCooperativeKernel((void*)k_persist, dim3(NBLK), dim3(512), args, 0, stream);
}